// Round 1
// baseline (3699.778 us; speedup 1.0000x reference)
//
#include <hip/hip_runtime.h>

#define EMB 64

// ---------------------------------------------------------------------------
// ego = concat(user_emb, item_emb); also write into all_e[:, 0:64]
// ---------------------------------------------------------------------------
__global__ void k_init_ego(const float* __restrict__ user_emb,
                           const float* __restrict__ item_emb,
                           float* __restrict__ ego, float* __restrict__ all_e,
                           int n_user, int N) {
    int idx = blockIdx.x * blockDim.x + threadIdx.x;
    int total = N * EMB;
    if (idx >= total) return;
    int n = idx >> 6;
    int c = idx & 63;
    float v = (n < n_user) ? user_emb[idx] : item_emb[(size_t)(n - n_user) * EMB + c];
    ego[idx] = v;
    all_e[(size_t)n * 256 + c] = v;
}

// ---------------------------------------------------------------------------
// side[dst] += w * ego[src]  — one wave (64 lanes) per edge, lane = component
// ---------------------------------------------------------------------------
__global__ void k_scatter(const float* __restrict__ ego,
                          const float* __restrict__ edge_w,
                          const int* __restrict__ src,
                          const int* __restrict__ dst,
                          float* __restrict__ side, int M) {
    long long idx = (long long)blockIdx.x * blockDim.x + threadIdx.x;
    long long e = idx >> 6;
    if (e >= M) return;
    int c = (int)(idx & 63);
    int s = src[e];
    int d = dst[e];
    float w = edge_w[e];
    atomicAdd(&side[(long long)d * EMB + c], w * ego[(long long)s * EMB + c]);
}

// ---------------------------------------------------------------------------
// new_ego = leaky_relu(side@Wgc + bgc + (ego*side)@Wbi + bbi, 0.2)
// all_e[:, col:col+64] = new_ego / max(||new_ego||, 1e-12); ego <- new_ego
// One wave per node row; W matrices staged in LDS; row broadcast via shfl.
// ---------------------------------------------------------------------------
__global__ __launch_bounds__(256) void k_transform(
        const float* __restrict__ ego_in, const float* __restrict__ side,
        const float* __restrict__ Wgc, const float* __restrict__ bgc,
        const float* __restrict__ Wbi, const float* __restrict__ bbi,
        float* __restrict__ ego_out, float* __restrict__ all_e,
        int N, int layer_col) {
    __shared__ float sWgc[EMB * EMB];
    __shared__ float sWbi[EMB * EMB];
    for (int i = threadIdx.x; i < EMB * EMB; i += blockDim.x) {
        sWgc[i] = Wgc[i];
        sWbi[i] = Wbi[i];
    }
    __syncthreads();

    int wave = threadIdx.x >> 6;
    int lane = threadIdx.x & 63;
    int n = blockIdx.x * 4 + wave;
    if (n >= N) return;

    float sv = side[(size_t)n * EMB + lane];
    float ev = ego_in[(size_t)n * EMB + lane];
    float acc = bgc[lane] + bbi[lane];
#pragma unroll
    for (int i = 0; i < EMB; i++) {
        float s_i = __shfl(sv, i, 64);
        float e_i = __shfl(ev, i, 64);
        acc += s_i * sWgc[i * EMB + lane] + (e_i * s_i) * sWbi[i * EMB + lane];
    }
    float val = acc > 0.f ? acc : 0.2f * acc;

    float ss = val * val;
#pragma unroll
    for (int off = 32; off > 0; off >>= 1) ss += __shfl_xor(ss, off, 64);
    float inv = 1.0f / fmaxf(sqrtf(ss), 1e-12f);

    all_e[(size_t)n * 256 + layer_col + lane] = val * inv;
    ego_out[(size_t)n * EMB + lane] = val;   // unnormalized carries forward
}

// ---------------------------------------------------------------------------
// out = [all_e[users], all_e[n_user+pos], all_e[n_user+neg]]  (each B x 256)
// ---------------------------------------------------------------------------
__global__ void k_gather(const float* __restrict__ all_e,
                         const int* __restrict__ users,
                         const int* __restrict__ pos,
                         const int* __restrict__ neg,
                         float* __restrict__ out, int n_user, int batch) {
    int idx = blockIdx.x * blockDim.x + threadIdx.x;
    int total = batch * 256;
    if (idx >= 3 * total) return;
    int which = idx / total;
    int r = idx - which * total;
    int b = r >> 8;
    int c = r & 255;
    int node;
    if (which == 0) node = users[b];
    else if (which == 1) node = n_user + pos[b];
    else node = n_user + neg[b];
    out[idx] = all_e[(size_t)node * 256 + c];
}

extern "C" void kernel_launch(void* const* d_in, const int* in_sizes, int n_in,
                              void* d_out, int out_size, void* d_ws, size_t ws_size,
                              hipStream_t stream) {
    const float* user_emb = (const float*)d_in[0];
    const float* item_emb = (const float*)d_in[1];
    const float* W_gc = (const float*)d_in[2];
    const float* b_gc = (const float*)d_in[3];
    const float* W_bi = (const float*)d_in[4];
    const float* b_bi = (const float*)d_in[5];
    const float* edge_w = (const float*)d_in[6];
    const int* edge_src = (const int*)d_in[7];
    const int* edge_dst = (const int*)d_in[8];
    const int* users = (const int*)d_in[9];
    const int* pos = (const int*)d_in[10];
    const int* neg = (const int*)d_in[11];

    int n_user = in_sizes[0] / EMB;
    int n_item = in_sizes[1] / EMB;
    int N = n_user + n_item;
    int M = in_sizes[6];
    int layers = in_sizes[2] / (EMB * EMB);
    int batch = in_sizes[9];
    float* out = (float*)d_out;

    float* ego = (float*)d_ws;                       // N*64 f32
    float* side = ego + (size_t)N * EMB;             // N*64 f32
    float* all_e = side + (size_t)N * EMB;           // N*256 f32

    k_init_ego<<<(N * EMB + 255) / 256, 256, 0, stream>>>(
        user_emb, item_emb, ego, all_e, n_user, N);

    for (int k = 0; k < layers; k++) {
        hipMemsetAsync(side, 0, (size_t)N * EMB * sizeof(float), stream);
        long long threads = (long long)M * 64;
        k_scatter<<<(int)((threads + 255) / 256), 256, 0, stream>>>(
            ego, edge_w, edge_src, edge_dst, side, M);
        k_transform<<<(N + 3) / 4, 256, 0, stream>>>(
            ego, side, W_gc + (size_t)k * EMB * EMB, b_gc + (size_t)k * EMB,
            W_bi + (size_t)k * EMB * EMB, b_bi + (size_t)k * EMB,
            ego, all_e, N, (k + 1) * EMB);
    }

    k_gather<<<(3 * batch * 256 + 255) / 256, 256, 0, stream>>>(
        all_e, users, pos, neg, out, n_user, batch);
}

// Round 2
// 1759.866 us; speedup vs baseline: 2.1023x; 2.1023x over previous
//
#include <hip/hip_runtime.h>

#define EMB 64

// ---------------------------------------------------------------------------
// ego = concat(user_emb, item_emb); also write into all_e[:, 0:64]
// ---------------------------------------------------------------------------
__global__ void k_init_ego(const float* __restrict__ user_emb,
                           const float* __restrict__ item_emb,
                           float* __restrict__ ego, float* __restrict__ all_e,
                           int n_user, int N) {
    int idx = blockIdx.x * blockDim.x + threadIdx.x;
    int total = N * EMB;
    if (idx >= total) return;
    int n = idx >> 6;
    int c = idx & 63;
    float v = (n < n_user) ? user_emb[idx] : item_emb[(size_t)(n - n_user) * EMB + c];
    ego[idx] = v;
    all_e[(size_t)n * 256 + c] = v;
}

// ---------------------------------------------------------------------------
// CSR build: histogram of dst
// ---------------------------------------------------------------------------
__global__ void k_hist(const int* __restrict__ dst, int* __restrict__ counts, int M) {
    int e = blockIdx.x * blockDim.x + threadIdx.x;
    if (e >= M) return;
    atomicAdd(&counts[dst[e]], 1);
}

// ---------------------------------------------------------------------------
// Exclusive scan over counts -> row_ptr[0..N], cursor = row_ptr copy.
// Single block, 1024 threads, chunked sequential + Hillis-Steele on partials.
// ---------------------------------------------------------------------------
__global__ __launch_bounds__(1024) void k_scan(const int* __restrict__ counts,
                                               int* __restrict__ row_ptr,
                                               int* __restrict__ cursor, int N) {
    __shared__ int part[1024];
    int tid = threadIdx.x;
    int T = 1024;
    int chunk = (N + T - 1) / T;
    int lo = tid * chunk;
    int hi = min(lo + chunk, N);
    int s = 0;
    for (int i = lo; i < hi; i++) s += counts[i];
    part[tid] = s;
    __syncthreads();
    for (int d = 1; d < T; d <<= 1) {
        int add = (tid >= d) ? part[tid - d] : 0;
        __syncthreads();
        part[tid] += add;
        __syncthreads();
    }
    int off = part[tid] - s;  // exclusive prefix of this chunk
    for (int i = lo; i < hi; i++) {
        row_ptr[i] = off;
        cursor[i] = off;
        off += counts[i];
    }
    if (tid == T - 1) row_ptr[N] = off;
}

// ---------------------------------------------------------------------------
// CSR fill: csr_sw[pos] = (src, bits(w)) at pos = cursor[dst]++
// ---------------------------------------------------------------------------
__global__ void k_fill(const int* __restrict__ src, const int* __restrict__ dst,
                       const float* __restrict__ w, int* __restrict__ cursor,
                       int2* __restrict__ csr_sw, int M) {
    int e = blockIdx.x * blockDim.x + threadIdx.x;
    if (e >= M) return;
    int d = dst[e];
    int pos = atomicAdd(&cursor[d], 1);
    csr_sw[pos] = make_int2(src[e], __float_as_int(w[e]));
}

// ---------------------------------------------------------------------------
// side[n] = sum_{e in row n} w_e * ego[src_e]   — one wave per node,
// lane = embedding component. No atomics; row written exactly once.
// ---------------------------------------------------------------------------
__global__ __launch_bounds__(256) void k_side(const int* __restrict__ row_ptr,
                                              const int2* __restrict__ csr_sw,
                                              const float* __restrict__ ego,
                                              float* __restrict__ side, int N) {
    int wave = threadIdx.x >> 6;
    int lane = threadIdx.x & 63;
    int n = blockIdx.x * 4 + wave;
    if (n >= N) return;
    int beg = row_ptr[n];
    int end = row_ptr[n + 1];
    float acc0 = 0.f, acc1 = 0.f;
    int e = beg;
    if ((end - beg) & 1) {
        int2 m = csr_sw[e];
        acc0 += __int_as_float(m.y) * ego[(size_t)m.x * EMB + lane];
        e++;
    }
    for (; e < end; e += 2) {
        int2 m0 = csr_sw[e];
        int2 m1 = csr_sw[e + 1];
        float v0 = ego[(size_t)m0.x * EMB + lane];
        float v1 = ego[(size_t)m1.x * EMB + lane];
        acc0 += __int_as_float(m0.y) * v0;
        acc1 += __int_as_float(m1.y) * v1;
    }
    side[(size_t)n * EMB + lane] = acc0 + acc1;
}

// ---------------------------------------------------------------------------
// Fused transform: out = leaky_relu(side@Wgc + bgc + (ego*side)@Wbi + bbi)
// ego <- out (in place, tile-local reads only); all_e[:,col] <- out/||out||.
// Register-blocked: thread = 4 rows x 16 cols; W broadcast from LDS (b128,
// same-address across lanes); X streamed from global as float4 (L1/L2 hits).
// ---------------------------------------------------------------------------
__global__ __launch_bounds__(256) void k_transform(
        const float* __restrict__ side, float* __restrict__ ego,
        const float* __restrict__ Wgc, const float* __restrict__ bgc,
        const float* __restrict__ Wbi, const float* __restrict__ bbi,
        float* __restrict__ all_e, int N, int layer_col) {
    __shared__ float sW[128][64];   // rows 0-63: Wgc, rows 64-127: Wbi
    __shared__ float sB[64];
    int tid = threadIdx.x;
    for (int i = tid; i < 64 * 64; i += 256) {
        sW[i >> 6][i & 63] = Wgc[i];
        sW[64 + (i >> 6)][i & 63] = Wbi[i];
    }
    if (tid < 64) sB[tid] = bgc[tid] + bbi[tid];
    __syncthreads();

    int cg = tid & 3;        // 4 col-groups of 16
    int rg = tid >> 2;       // 64 row-groups of 4
    int c0 = cg * 16;
    int r0 = blockIdx.x * 256 + rg * 4;

    float acc[4][16];
#pragma unroll
    for (int rr = 0; rr < 4; rr++)
#pragma unroll
        for (int c = 0; c < 16; c++) acc[rr][c] = sB[c0 + c];

    int ri[4];
#pragma unroll
    for (int rr = 0; rr < 4; rr++) ri[rr] = min(r0 + rr, N - 1);

    const float4* side4 = (const float4*)side;
    const float4* ego4 = (const float4*)ego;

    // phase 1: side @ Wgc
#pragma unroll 1
    for (int kq = 0; kq < 16; kq++) {
        float4 x[4];
#pragma unroll
        for (int rr = 0; rr < 4; rr++) x[rr] = side4[(size_t)ri[rr] * 16 + kq];
#pragma unroll
        for (int kk = 0; kk < 4; kk++) {
            int k = kq * 4 + kk;
#pragma unroll
            for (int cq = 0; cq < 4; cq++) {
                float4 w = *(const float4*)&sW[k][c0 + cq * 4];
#pragma unroll
                for (int rr = 0; rr < 4; rr++) {
                    float xv = (&x[rr].x)[kk];
                    acc[rr][cq * 4 + 0] += xv * w.x;
                    acc[rr][cq * 4 + 1] += xv * w.y;
                    acc[rr][cq * 4 + 2] += xv * w.z;
                    acc[rr][cq * 4 + 3] += xv * w.w;
                }
            }
        }
    }

    // phase 2: (ego*side) @ Wbi
#pragma unroll 1
    for (int kq = 0; kq < 16; kq++) {
        float4 x[4];
#pragma unroll
        for (int rr = 0; rr < 4; rr++) {
            float4 a = ego4[(size_t)ri[rr] * 16 + kq];
            float4 b = side4[(size_t)ri[rr] * 16 + kq];
            x[rr] = make_float4(a.x * b.x, a.y * b.y, a.z * b.z, a.w * b.w);
        }
#pragma unroll
        for (int kk = 0; kk < 4; kk++) {
            int k = 64 + kq * 4 + kk;
#pragma unroll
            for (int cq = 0; cq < 4; cq++) {
                float4 w = *(const float4*)&sW[k][c0 + cq * 4];
#pragma unroll
                for (int rr = 0; rr < 4; rr++) {
                    float xv = (&x[rr].x)[kk];
                    acc[rr][cq * 4 + 0] += xv * w.x;
                    acc[rr][cq * 4 + 1] += xv * w.y;
                    acc[rr][cq * 4 + 2] += xv * w.z;
                    acc[rr][cq * 4 + 3] += xv * w.w;
                }
            }
        }
    }

    // epilogue: leaky relu, row norm (4 col-groups live in lanes tid^{1,2}),
    // write ego (unnormalized) and all_e (normalized)
#pragma unroll
    for (int rr = 0; rr < 4; rr++) {
        float s = 0.f;
#pragma unroll
        for (int c = 0; c < 16; c++) {
            float v = acc[rr][c];
            v = v > 0.f ? v : 0.2f * v;
            acc[rr][c] = v;
            s += v * v;
        }
        s += __shfl_xor(s, 1, 64);
        s += __shfl_xor(s, 2, 64);
        float inv = 1.0f / fmaxf(sqrtf(s), 1e-12f);
        int row = r0 + rr;
        if (row < N) {
            float4* pe = (float4*)&ego[(size_t)row * EMB + c0];
            float4* pa = (float4*)&all_e[(size_t)row * 256 + layer_col + c0];
#pragma unroll
            for (int cq = 0; cq < 4; cq++) {
                float4 v = make_float4(acc[rr][cq * 4 + 0], acc[rr][cq * 4 + 1],
                                       acc[rr][cq * 4 + 2], acc[rr][cq * 4 + 3]);
                pe[cq] = v;
                pa[cq] = make_float4(v.x * inv, v.y * inv, v.z * inv, v.w * inv);
            }
        }
    }
}

// ---------------------------------------------------------------------------
// out = [all_e[users], all_e[n_user+pos], all_e[n_user+neg]]  (each B x 256)
// ---------------------------------------------------------------------------
__global__ void k_gather(const float* __restrict__ all_e,
                         const int* __restrict__ users,
                         const int* __restrict__ pos,
                         const int* __restrict__ neg,
                         float* __restrict__ out, int n_user, int batch) {
    int idx = blockIdx.x * blockDim.x + threadIdx.x;
    int total = batch * 256;
    if (idx >= 3 * total) return;
    int which = idx / total;
    int r = idx - which * total;
    int b = r >> 8;
    int c = r & 255;
    int node;
    if (which == 0) node = users[b];
    else if (which == 1) node = n_user + pos[b];
    else node = n_user + neg[b];
    out[idx] = all_e[(size_t)node * 256 + c];
}

static inline size_t align256(size_t x) { return (x + 255) & ~(size_t)255; }

extern "C" void kernel_launch(void* const* d_in, const int* in_sizes, int n_in,
                              void* d_out, int out_size, void* d_ws, size_t ws_size,
                              hipStream_t stream) {
    const float* user_emb = (const float*)d_in[0];
    const float* item_emb = (const float*)d_in[1];
    const float* W_gc = (const float*)d_in[2];
    const float* b_gc = (const float*)d_in[3];
    const float* W_bi = (const float*)d_in[4];
    const float* b_bi = (const float*)d_in[5];
    const float* edge_w = (const float*)d_in[6];
    const int* edge_src = (const int*)d_in[7];
    const int* edge_dst = (const int*)d_in[8];
    const int* users = (const int*)d_in[9];
    const int* pos = (const int*)d_in[10];
    const int* neg = (const int*)d_in[11];

    int n_user = in_sizes[0] / EMB;
    int n_item = in_sizes[1] / EMB;
    int N = n_user + n_item;
    int M = in_sizes[6];
    int layers = in_sizes[2] / (EMB * EMB);
    int batch = in_sizes[9];
    float* out = (float*)d_out;

    // workspace carve
    char* p = (char*)d_ws;
    float* ego = (float*)p;     p += align256((size_t)N * EMB * 4);
    float* side = (float*)p;    p += align256((size_t)N * EMB * 4);
    float* all_e = (float*)p;   p += align256((size_t)N * 256 * 4);
    int* counts = (int*)p;      p += align256((size_t)N * 4);
    int* row_ptr = (int*)p;     p += align256((size_t)(N + 1) * 4);
    int* cursor = (int*)p;      p += align256((size_t)N * 4);
    int2* csr_sw = (int2*)p;    p += align256((size_t)M * 8);

    hipMemsetAsync(counts, 0, (size_t)N * 4, stream);

    k_init_ego<<<(N * EMB + 255) / 256, 256, 0, stream>>>(
        user_emb, item_emb, ego, all_e, n_user, N);

    // CSR build (once per launch; reused by all 3 layers)
    k_hist<<<(M + 255) / 256, 256, 0, stream>>>(edge_dst, counts, M);
    k_scan<<<1, 1024, 0, stream>>>(counts, row_ptr, cursor, N);
    k_fill<<<(M + 255) / 256, 256, 0, stream>>>(edge_src, edge_dst, edge_w,
                                                cursor, csr_sw, M);

    for (int k = 0; k < layers; k++) {
        k_side<<<(N + 3) / 4, 256, 0, stream>>>(row_ptr, csr_sw, ego, side, N);
        k_transform<<<(N + 255) / 256, 256, 0, stream>>>(
            side, ego, W_gc + (size_t)k * EMB * EMB, b_gc + (size_t)k * EMB,
            W_bi + (size_t)k * EMB * EMB, b_bi + (size_t)k * EMB,
            all_e, N, (k + 1) * EMB);
    }

    k_gather<<<(3 * batch * 256 + 255) / 256, 256, 0, stream>>>(
        all_e, users, pos, neg, out, n_user, batch);
}

// Round 3
// 1299.115 us; speedup vs baseline: 2.8479x; 1.3547x over previous
//
#include <hip/hip_runtime.h>

#define EMB 64

// ---------------------------------------------------------------------------
// ego = concat(user_emb, item_emb); also write into all_e[:, 0:64]
// ---------------------------------------------------------------------------
__global__ void k_init_ego(const float* __restrict__ user_emb,
                           const float* __restrict__ item_emb,
                           float* __restrict__ ego, float* __restrict__ all_e,
                           int n_user, int N) {
    int idx = blockIdx.x * blockDim.x + threadIdx.x;
    int total = N * EMB;
    if (idx >= total) return;
    int n = idx >> 6;
    int c = idx & 63;
    float v = (n < n_user) ? user_emb[idx] : item_emb[(size_t)(n - n_user) * EMB + c];
    ego[idx] = v;
    all_e[(size_t)n * 256 + c] = v;
}

// ---------------------------------------------------------------------------
// CSR build: histogram of dst
// ---------------------------------------------------------------------------
__global__ void k_hist(const int* __restrict__ dst, int* __restrict__ counts, int M) {
    int e = blockIdx.x * blockDim.x + threadIdx.x;
    if (e >= M) return;
    atomicAdd(&counts[dst[e]], 1);
}

// ---------------------------------------------------------------------------
// Scan stage 1: per-block (256 elems) sum of counts -> partial[block]
// ---------------------------------------------------------------------------
__global__ __launch_bounds__(256) void k_blocksum(const int* __restrict__ counts,
                                                  int* __restrict__ partial, int N) {
    int i = blockIdx.x * 256 + threadIdx.x;
    int v = (i < N) ? counts[i] : 0;
#pragma unroll
    for (int off = 32; off > 0; off >>= 1) v += __shfl_down(v, off, 64);
    __shared__ int ws[4];
    int wave = threadIdx.x >> 6, lane = threadIdx.x & 63;
    if (lane == 0) ws[wave] = v;
    __syncthreads();
    if (threadIdx.x == 0) partial[blockIdx.x] = ws[0] + ws[1] + ws[2] + ws[3];
}

// ---------------------------------------------------------------------------
// Scan stage 2: exclusive scan of P partials in-place (single block, tiled)
// ---------------------------------------------------------------------------
__global__ __launch_bounds__(1024) void k_scan_partials(int* __restrict__ partial, int P) {
    __shared__ int buf[1024];
    int tid = threadIdx.x;
    int carry = 0;
    for (int base = 0; base < P; base += 1024) {
        int i = base + tid;
        int v = (i < P) ? partial[i] : 0;
        buf[tid] = v;
        __syncthreads();
        for (int d = 1; d < 1024; d <<= 1) {
            int add = (tid >= d) ? buf[tid - d] : 0;
            __syncthreads();
            buf[tid] += add;
            __syncthreads();
        }
        if (i < P) partial[i] = carry + buf[tid] - v;   // exclusive
        carry += buf[1023];
        __syncthreads();
    }
}

// ---------------------------------------------------------------------------
// Scan stage 3: per-block exclusive scan + block offset -> row_ptr, cursor
// ---------------------------------------------------------------------------
__global__ __launch_bounds__(256) void k_rowptr(const int* __restrict__ counts,
                                                const int* __restrict__ partial,
                                                int* __restrict__ row_ptr,
                                                int* __restrict__ cursor, int N) {
    __shared__ int buf[256];
    int tid = threadIdx.x;
    int i = blockIdx.x * 256 + tid;
    int c = (i < N) ? counts[i] : 0;
    buf[tid] = c;
    __syncthreads();
    for (int d = 1; d < 256; d <<= 1) {
        int add = (tid >= d) ? buf[tid - d] : 0;
        __syncthreads();
        buf[tid] += add;
        __syncthreads();
    }
    int off = partial[blockIdx.x] + buf[tid] - c;   // exclusive prefix
    if (i < N) {
        row_ptr[i] = off;
        cursor[i] = off;
        if (i == N - 1) row_ptr[N] = off + c;
    }
}

// ---------------------------------------------------------------------------
// CSR fill: csr_sw[pos] = (src, bits(w)) at pos = cursor[dst]++
// ---------------------------------------------------------------------------
__global__ void k_fill(const int* __restrict__ src, const int* __restrict__ dst,
                       const float* __restrict__ w, int* __restrict__ cursor,
                       int2* __restrict__ csr_sw, int M) {
    int e = blockIdx.x * blockDim.x + threadIdx.x;
    if (e >= M) return;
    int d = dst[e];
    int pos = atomicAdd(&cursor[d], 1);
    csr_sw[pos] = make_int2(src[e], __float_as_int(w[e]));
}

// ---------------------------------------------------------------------------
// side[n] = sum_{e in row n} w_e * ego[src_e]   — one wave per node,
// lane = embedding component. 4-deep unroll, int4 metadata loads.
// ---------------------------------------------------------------------------
__global__ __launch_bounds__(256) void k_side(const int* __restrict__ row_ptr,
                                              const int2* __restrict__ csr_sw,
                                              const float* __restrict__ ego,
                                              float* __restrict__ side, int N) {
    int wave = threadIdx.x >> 6;
    int lane = threadIdx.x & 63;
    int n = blockIdx.x * 4 + wave;
    if (n >= N) return;
    int beg = row_ptr[n];
    int end = row_ptr[n + 1];
    float a0 = 0.f, a1 = 0.f, a2 = 0.f, a3 = 0.f;
    int e = beg;
    if ((e & 1) && e < end) {                 // peel to 16B alignment
        int2 m = csr_sw[e];
        a0 += __int_as_float(m.y) * ego[(size_t)m.x * EMB + lane];
        e++;
    }
    for (; e + 4 <= end; e += 4) {
        int4 p0 = *(const int4*)(csr_sw + e);
        int4 p1 = *(const int4*)(csr_sw + e + 2);
        a0 += __int_as_float(p0.y) * ego[(size_t)p0.x * EMB + lane];
        a1 += __int_as_float(p0.w) * ego[(size_t)p0.z * EMB + lane];
        a2 += __int_as_float(p1.y) * ego[(size_t)p1.x * EMB + lane];
        a3 += __int_as_float(p1.w) * ego[(size_t)p1.z * EMB + lane];
    }
    for (; e < end; e++) {
        int2 m = csr_sw[e];
        a0 += __int_as_float(m.y) * ego[(size_t)m.x * EMB + lane];
    }
    side[(size_t)n * EMB + lane] = (a0 + a1) + (a2 + a3);
}

// ---------------------------------------------------------------------------
// Fused transform: out = leaky_relu(side@Wgc + bgc + (ego*side)@Wbi + bbi)
// ego <- out (in place); all_e[:,col] <- out/||out||.
// Thread = 4 rows x 16 cols; W broadcast from LDS; X from global as float4.
// ---------------------------------------------------------------------------
__global__ __launch_bounds__(256) void k_transform(
        const float* __restrict__ side, float* __restrict__ ego,
        const float* __restrict__ Wgc, const float* __restrict__ bgc,
        const float* __restrict__ Wbi, const float* __restrict__ bbi,
        float* __restrict__ all_e, int N, int layer_col) {
    __shared__ float sW[128][64];   // rows 0-63: Wgc, rows 64-127: Wbi
    __shared__ float sB[64];
    int tid = threadIdx.x;
    for (int i = tid; i < 64 * 64; i += 256) {
        sW[i >> 6][i & 63] = Wgc[i];
        sW[64 + (i >> 6)][i & 63] = Wbi[i];
    }
    if (tid < 64) sB[tid] = bgc[tid] + bbi[tid];
    __syncthreads();

    int cg = tid & 3;        // 4 col-groups of 16
    int rg = tid >> 2;       // 64 row-groups of 4
    int c0 = cg * 16;
    int r0 = blockIdx.x * 256 + rg * 4;

    float acc[4][16];
#pragma unroll
    for (int rr = 0; rr < 4; rr++)
#pragma unroll
        for (int c = 0; c < 16; c++) acc[rr][c] = sB[c0 + c];

    int ri[4];
#pragma unroll
    for (int rr = 0; rr < 4; rr++) ri[rr] = min(r0 + rr, N - 1);

    const float4* side4 = (const float4*)side;
    const float4* ego4 = (const float4*)ego;

    // phase 1: side @ Wgc
#pragma unroll 1
    for (int kq = 0; kq < 16; kq++) {
        float4 x[4];
#pragma unroll
        for (int rr = 0; rr < 4; rr++) x[rr] = side4[(size_t)ri[rr] * 16 + kq];
#pragma unroll
        for (int kk = 0; kk < 4; kk++) {
            int k = kq * 4 + kk;
#pragma unroll
            for (int cq = 0; cq < 4; cq++) {
                float4 w = *(const float4*)&sW[k][c0 + cq * 4];
#pragma unroll
                for (int rr = 0; rr < 4; rr++) {
                    float xv = (&x[rr].x)[kk];
                    acc[rr][cq * 4 + 0] += xv * w.x;
                    acc[rr][cq * 4 + 1] += xv * w.y;
                    acc[rr][cq * 4 + 2] += xv * w.z;
                    acc[rr][cq * 4 + 3] += xv * w.w;
                }
            }
        }
    }

    // phase 2: (ego*side) @ Wbi
#pragma unroll 1
    for (int kq = 0; kq < 16; kq++) {
        float4 x[4];
#pragma unroll
        for (int rr = 0; rr < 4; rr++) {
            float4 a = ego4[(size_t)ri[rr] * 16 + kq];
            float4 b = side4[(size_t)ri[rr] * 16 + kq];
            x[rr] = make_float4(a.x * b.x, a.y * b.y, a.z * b.z, a.w * b.w);
        }
#pragma unroll
        for (int kk = 0; kk < 4; kk++) {
            int k = 64 + kq * 4 + kk;
#pragma unroll
            for (int cq = 0; cq < 4; cq++) {
                float4 w = *(const float4*)&sW[k][c0 + cq * 4];
#pragma unroll
                for (int rr = 0; rr < 4; rr++) {
                    float xv = (&x[rr].x)[kk];
                    acc[rr][cq * 4 + 0] += xv * w.x;
                    acc[rr][cq * 4 + 1] += xv * w.y;
                    acc[rr][cq * 4 + 2] += xv * w.z;
                    acc[rr][cq * 4 + 3] += xv * w.w;
                }
            }
        }
    }

    // epilogue: leaky relu, row norm, write ego + normalized all_e
#pragma unroll
    for (int rr = 0; rr < 4; rr++) {
        float s = 0.f;
#pragma unroll
        for (int c = 0; c < 16; c++) {
            float v = acc[rr][c];
            v = v > 0.f ? v : 0.2f * v;
            acc[rr][c] = v;
            s += v * v;
        }
        s += __shfl_xor(s, 1, 64);
        s += __shfl_xor(s, 2, 64);
        float inv = 1.0f / fmaxf(sqrtf(s), 1e-12f);
        int row = r0 + rr;
        if (row < N) {
            float4* pe = (float4*)&ego[(size_t)row * EMB + c0];
            float4* pa = (float4*)&all_e[(size_t)row * 256 + layer_col + c0];
#pragma unroll
            for (int cq = 0; cq < 4; cq++) {
                float4 v = make_float4(acc[rr][cq * 4 + 0], acc[rr][cq * 4 + 1],
                                       acc[rr][cq * 4 + 2], acc[rr][cq * 4 + 3]);
                pe[cq] = v;
                pa[cq] = make_float4(v.x * inv, v.y * inv, v.z * inv, v.w * inv);
            }
        }
    }
}

// ---------------------------------------------------------------------------
// out = [all_e[users], all_e[n_user+pos], all_e[n_user+neg]]  (each B x 256)
// ---------------------------------------------------------------------------
__global__ void k_gather(const float* __restrict__ all_e,
                         const int* __restrict__ users,
                         const int* __restrict__ pos,
                         const int* __restrict__ neg,
                         float* __restrict__ out, int n_user, int batch) {
    int idx = blockIdx.x * blockDim.x + threadIdx.x;
    int total = batch * 256;
    if (idx >= 3 * total) return;
    int which = idx / total;
    int r = idx - which * total;
    int b = r >> 8;
    int c = r & 255;
    int node;
    if (which == 0) node = users[b];
    else if (which == 1) node = n_user + pos[b];
    else node = n_user + neg[b];
    out[idx] = all_e[(size_t)node * 256 + c];
}

static inline size_t align256(size_t x) { return (x + 255) & ~(size_t)255; }

extern "C" void kernel_launch(void* const* d_in, const int* in_sizes, int n_in,
                              void* d_out, int out_size, void* d_ws, size_t ws_size,
                              hipStream_t stream) {
    const float* user_emb = (const float*)d_in[0];
    const float* item_emb = (const float*)d_in[1];
    const float* W_gc = (const float*)d_in[2];
    const float* b_gc = (const float*)d_in[3];
    const float* W_bi = (const float*)d_in[4];
    const float* b_bi = (const float*)d_in[5];
    const float* edge_w = (const float*)d_in[6];
    const int* edge_src = (const int*)d_in[7];
    const int* edge_dst = (const int*)d_in[8];
    const int* users = (const int*)d_in[9];
    const int* pos = (const int*)d_in[10];
    const int* neg = (const int*)d_in[11];

    int n_user = in_sizes[0] / EMB;
    int n_item = in_sizes[1] / EMB;
    int N = n_user + n_item;
    int M = in_sizes[6];
    int layers = in_sizes[2] / (EMB * EMB);
    int batch = in_sizes[9];
    float* out = (float*)d_out;

    int nblk = (N + 255) / 256;   // scan blocks

    // workspace carve
    char* p = (char*)d_ws;
    float* ego = (float*)p;     p += align256((size_t)N * EMB * 4);
    float* side = (float*)p;    p += align256((size_t)N * EMB * 4);
    float* all_e = (float*)p;   p += align256((size_t)N * 256 * 4);
    int* counts = (int*)p;      p += align256((size_t)N * 4);
    int* row_ptr = (int*)p;     p += align256((size_t)(N + 1) * 4);
    int* cursor = (int*)p;      p += align256((size_t)N * 4);
    int* partial = (int*)p;     p += align256((size_t)nblk * 4);
    int2* csr_sw = (int2*)p;    p += align256((size_t)M * 8);

    hipMemsetAsync(counts, 0, (size_t)N * 4, stream);

    k_init_ego<<<(N * EMB + 255) / 256, 256, 0, stream>>>(
        user_emb, item_emb, ego, all_e, n_user, N);

    // CSR build (once per launch; reused by all 3 layers)
    k_hist<<<(M + 255) / 256, 256, 0, stream>>>(edge_dst, counts, M);
    k_blocksum<<<nblk, 256, 0, stream>>>(counts, partial, N);
    k_scan_partials<<<1, 1024, 0, stream>>>(partial, nblk);
    k_rowptr<<<nblk, 256, 0, stream>>>(counts, partial, row_ptr, cursor, N);
    k_fill<<<(M + 255) / 256, 256, 0, stream>>>(edge_src, edge_dst, edge_w,
                                                cursor, csr_sw, M);

    for (int k = 0; k < layers; k++) {
        k_side<<<(N + 3) / 4, 256, 0, stream>>>(row_ptr, csr_sw, ego, side, N);
        k_transform<<<(N + 255) / 256, 256, 0, stream>>>(
            side, ego, W_gc + (size_t)k * EMB * EMB, b_gc + (size_t)k * EMB,
            W_bi + (size_t)k * EMB * EMB, b_bi + (size_t)k * EMB,
            all_e, N, (k + 1) * EMB);
    }

    k_gather<<<(3 * batch * 256 + 255) / 256, 256, 0, stream>>>(
        all_e, users, pos, neg, out, n_user, batch);
}